// Round 1
// baseline (938.763 us; speedup 1.0000x reference)
//
#include <hip/hip_runtime.h>
#include <math.h>

#define R 1024
#define CIN 256
#define CHID 32
#define NH 8
#define CZ 128
#define EPS 1e-5f

// ---------------- K1: mn = LayerNorm(m) ----------------
__global__ __launch_bounds__(256) void k_ln_m(const float* __restrict__ m,
        const float* __restrict__ w, const float* __restrict__ b,
        float* __restrict__ mn) {
    int row = blockIdx.x;
    int tid = threadIdx.x;
    float x = m[row * CIN + tid];
    float s1 = x, s2 = x * x;
    #pragma unroll
    for (int mm = 1; mm < 64; mm <<= 1) {
        s1 += __shfl_xor(s1, mm);
        s2 += __shfl_xor(s2, mm);
    }
    __shared__ float red[8];
    int wave = tid >> 6;
    if ((tid & 63) == 0) { red[wave * 2] = s1; red[wave * 2 + 1] = s2; }
    __syncthreads();
    float t1 = red[0] + red[2] + red[4] + red[6];
    float t2 = red[1] + red[3] + red[5] + red[7];
    float mu = t1 * (1.0f / CIN);
    float var = t2 * (1.0f / CIN) - mu * mu;
    float rstd = rsqrtf(var + EPS);
    mn[row * CIN + tid] = (x - mu) * rstd * w[tid] + b[tid];
}

// ---------------- K2: QS/KS/VS/GS = mn @ {Wq,Wk,Wv,Wg} (+scale / sigmoid) ----
// grid = 4 mats * 64 row-tiles; block computes 16 rows x 256 cols.
__global__ __launch_bounds__(256) void k_qkvg(const float* __restrict__ mn,
        const float* __restrict__ Wq, const float* __restrict__ Wk,
        const float* __restrict__ Wv, const float* __restrict__ Wg,
        float* __restrict__ QS, float* __restrict__ KS,
        float* __restrict__ VS, float* __restrict__ GS) {
    __shared__ __align__(16) float mnt[256 * 16];  // transposed: mnt[c][r]
    int tid = threadIdx.x;
    int mat = blockIdx.x >> 6;
    int qb = (blockIdx.x & 63) * 16;
    #pragma unroll
    for (int r = 0; r < 16; ++r)
        mnt[tid * 16 + r] = mn[(qb + r) * CIN + tid];
    __syncthreads();
    const float* W = (mat == 0) ? Wq : (mat == 1) ? Wk : (mat == 2) ? Wv : Wg;
    float acc[16];
    #pragma unroll
    for (int r = 0; r < 16; ++r) acc[r] = 0.f;
    const float4* mt4 = (const float4*)mnt;
    #pragma unroll 4
    for (int c = 0; c < 256; ++c) {
        float wv = W[c * 256 + tid];
        float4 a = mt4[c * 4 + 0];
        float4 b4 = mt4[c * 4 + 1];
        float4 c4 = mt4[c * 4 + 2];
        float4 d4 = mt4[c * 4 + 3];
        acc[0] += a.x * wv;  acc[1] += a.y * wv;  acc[2] += a.z * wv;  acc[3] += a.w * wv;
        acc[4] += b4.x * wv; acc[5] += b4.y * wv; acc[6] += b4.z * wv; acc[7] += b4.w * wv;
        acc[8] += c4.x * wv; acc[9] += c4.y * wv; acc[10] += c4.z * wv; acc[11] += c4.w * wv;
        acc[12] += d4.x * wv; acc[13] += d4.y * wv; acc[14] += d4.z * wv; acc[15] += d4.w * wv;
    }
    float* OUT = (mat == 0) ? QS : (mat == 1) ? KS : (mat == 2) ? VS : GS;
    #pragma unroll
    for (int r = 0; r < 16; ++r) {
        float v = acc[r];
        if (mat == 0) v *= 0.17677669529663687f;      // 1/sqrt(32)
        if (mat == 3) v = 1.f / (1.f + __expf(-v));   // sigmoid (no bias in ref)
        OUT[(qb + r) * 256 + tid] = v;
    }
}

// ---------------- K3: fused pair-bias(z) + attention + gate ----------------
// One block per query row q. 256 threads, 4 blocks/CU target.
__global__ __launch_bounds__(256, 4) void k_attn(
        const float* __restrict__ z, const float* __restrict__ lzw,
        const float* __restrict__ lzb, const float* __restrict__ Wz,
        const float* __restrict__ QS, const float* __restrict__ KS,
        const float* __restrict__ VS, const float* __restrict__ GS,
        float* __restrict__ OB) {
    __shared__ __align__(16) float s_lds[NH * R];      // 32 KB scores [h][k]
    __shared__ __align__(16) float q_lds[CIN];         // this q row (prescaled)
    __shared__ __align__(16) float A_lds[CZ * NH];     // A[c][h] = lzw[c]*Wz[c][h]
    __shared__ float sumA[NH], constB[NH], inv_lds[NH];
    int tid = threadIdx.x;
    int q = blockIdx.x;

    // ---- prep ----
    if (tid < CZ) {
        float lw = lzw[tid];
        #pragma unroll
        for (int h = 0; h < NH; ++h) A_lds[tid * NH + h] = lw * Wz[tid * NH + h];
    }
    q_lds[tid] = QS[q * CIN + tid];
    __syncthreads();
    if (tid < NH) {
        float sa = 0.f, cb = 0.f;
        #pragma unroll 8
        for (int c = 0; c < CZ; ++c) {
            sa += A_lds[c * NH + tid];
            cb += lzb[c] * Wz[c * NH + tid];
        }
        sumA[tid] = sa; constB[tid] = cb;
    }
    __syncthreads();

    // ---- phase 1: scores s[h][k] = q.k + bias(z[q,k,:]) ----
    const float4* A4 = (const float4*)A_lds;
    const float4* Qr = (const float4*)q_lds;
    for (int it = 0; it < 4; ++it) {
        int k = it * 256 + tid;
        const float4* zr = (const float4*)(z + ((size_t)q * R + (size_t)k) * CZ);
        float s1 = 0.f, s2 = 0.f;
        float d[NH];
        #pragma unroll
        for (int h = 0; h < NH; ++h) d[h] = 0.f;
        #pragma unroll 4
        for (int c4 = 0; c4 < 32; ++c4) {
            float4 zv = zr[c4];
            #pragma unroll
            for (int e = 0; e < 4; ++e) {
                float x = (e == 0) ? zv.x : (e == 1) ? zv.y : (e == 2) ? zv.z : zv.w;
                float4 aa = A4[(c4 * 4 + e) * 2];
                float4 ab = A4[(c4 * 4 + e) * 2 + 1];
                s1 += x; s2 += x * x;
                d[0] += x * aa.x; d[1] += x * aa.y; d[2] += x * aa.z; d[3] += x * aa.w;
                d[4] += x * ab.x; d[5] += x * ab.y; d[6] += x * ab.z; d[7] += x * ab.w;
            }
        }
        float mu = s1 * (1.0f / CZ);
        float var = s2 * (1.0f / CZ) - mu * mu;
        float rstd = rsqrtf(var + EPS);
        const float4* Kr = (const float4*)(KS + (size_t)k * CIN);
        #pragma unroll 2
        for (int h = 0; h < NH; ++h) {
            float bias = rstd * (d[h] - mu * sumA[h]) + constB[h];
            float qd = 0.f;
            #pragma unroll
            for (int j = 0; j < 8; ++j) {
                float4 kv = Kr[h * 8 + j];
                float4 qv = Qr[h * 8 + j];
                qd += kv.x * qv.x + kv.y * qv.y + kv.z * qv.z + kv.w * qv.w;
            }
            s_lds[h * R + k] = qd + bias;
        }
    }
    __syncthreads();

    // ---- phase 2: softmax per head (32 lanes per head) ----
    {
        int r = tid >> 5, j = tid & 31;
        float* srow = s_lds + r * R;
        float mx = -1e30f;
        #pragma unroll 4
        for (int i = 0; i < 32; ++i) mx = fmaxf(mx, srow[j + i * 32]);
        #pragma unroll
        for (int mm = 1; mm < 32; mm <<= 1) mx = fmaxf(mx, __shfl_xor(mx, mm));
        float sum = 0.f;
        #pragma unroll 4
        for (int i = 0; i < 32; ++i) {
            float e = __expf(srow[j + i * 32] - mx);
            srow[j + i * 32] = e;
            sum += e;
        }
        #pragma unroll
        for (int mm = 1; mm < 32; mm <<= 1) sum += __shfl_xor(sum, mm);
        if (j == 0) inv_lds[r] = 1.f / sum;
    }
    __syncthreads();

    // ---- phase 3: o[h,d] = (sum_k p*V) * inv * g ----
    {
        int h = tid >> 5;
        const float* prow = s_lds + h * R;
        const float* Vp = VS + tid;   // V[k][h*32+d] ; tid == h*32+d
        float o0 = 0.f, o1 = 0.f, o2 = 0.f, o3 = 0.f;
        #pragma unroll 2
        for (int k2 = 0; k2 < R; k2 += 4) {
            o0 += prow[k2 + 0] * Vp[(k2 + 0) * 256];
            o1 += prow[k2 + 1] * Vp[(k2 + 1) * 256];
            o2 += prow[k2 + 2] * Vp[(k2 + 2) * 256];
            o3 += prow[k2 + 3] * Vp[(k2 + 3) * 256];
        }
        float o = ((o0 + o1) + (o2 + o3)) * inv_lds[h];
        float g = GS[q * CIN + tid];
        OB[q * CIN + tid] = o * g;
    }
}

// ---------------- K4: out = OB @ Wo + bo ----------------
__global__ __launch_bounds__(256) void k_out(const float* __restrict__ OB,
        const float* __restrict__ Wo, const float* __restrict__ bo,
        float* __restrict__ out) {
    __shared__ __align__(16) float mnt[256 * 16];
    int tid = threadIdx.x;
    int qb = blockIdx.x * 16;
    #pragma unroll
    for (int r = 0; r < 16; ++r)
        mnt[tid * 16 + r] = OB[(qb + r) * CIN + tid];
    __syncthreads();
    float acc[16];
    #pragma unroll
    for (int r = 0; r < 16; ++r) acc[r] = 0.f;
    const float4* mt4 = (const float4*)mnt;
    #pragma unroll 4
    for (int c = 0; c < 256; ++c) {
        float wv = Wo[c * 256 + tid];
        float4 a = mt4[c * 4 + 0];
        float4 b4 = mt4[c * 4 + 1];
        float4 c4 = mt4[c * 4 + 2];
        float4 d4 = mt4[c * 4 + 3];
        acc[0] += a.x * wv;  acc[1] += a.y * wv;  acc[2] += a.z * wv;  acc[3] += a.w * wv;
        acc[4] += b4.x * wv; acc[5] += b4.y * wv; acc[6] += b4.z * wv; acc[7] += b4.w * wv;
        acc[8] += c4.x * wv; acc[9] += c4.y * wv; acc[10] += c4.z * wv; acc[11] += c4.w * wv;
        acc[12] += d4.x * wv; acc[13] += d4.y * wv; acc[14] += d4.z * wv; acc[15] += d4.w * wv;
    }
    float bv = bo[tid];
    #pragma unroll
    for (int r = 0; r < 16; ++r)
        out[(qb + r) * 256 + tid] = acc[r] + bv;
}

extern "C" void kernel_launch(void* const* d_in, const int* in_sizes, int n_in,
                              void* d_out, int out_size, void* d_ws, size_t ws_size,
                              hipStream_t stream) {
    (void)in_sizes; (void)n_in; (void)out_size; (void)ws_size;
    const float* m   = (const float*)d_in[0];
    const float* z   = (const float*)d_in[1];
    const float* lmw = (const float*)d_in[2];
    const float* lmb = (const float*)d_in[3];
    const float* lzw = (const float*)d_in[4];
    const float* lzb = (const float*)d_in[5];
    const float* Wz  = (const float*)d_in[6];
    const float* Wq  = (const float*)d_in[7];
    const float* Wk  = (const float*)d_in[8];
    const float* Wv  = (const float*)d_in[9];
    const float* Wg  = (const float*)d_in[10];
    // d_in[11] = bg : unused by the reference
    const float* Wo  = (const float*)d_in[12];
    const float* bo  = (const float*)d_in[13];
    float* ws = (float*)d_ws;
    float* MN = ws;                 // 1024*256
    float* QS = ws + 262144;
    float* KS = ws + 524288;
    float* VS = ws + 786432;
    float* GS = ws + 1048576;
    float* OB = ws + 1310720;       // end at 1572864 floats = 6 MB
    float* out = (float*)d_out;

    hipLaunchKernelGGL(k_ln_m, dim3(R), dim3(256), 0, stream, m, lmw, lmb, MN);
    hipLaunchKernelGGL(k_qkvg, dim3(256), dim3(256), 0, stream,
                       MN, Wq, Wk, Wv, Wg, QS, KS, VS, GS);
    hipLaunchKernelGGL(k_attn, dim3(R), dim3(256), 0, stream,
                       z, lzw, lzb, Wz, QS, KS, VS, GS, OB);
    hipLaunchKernelGGL(k_out, dim3(64), dim3(256), 0, stream, OB, Wo, bo, out);
}